// Round 6
// baseline (3502.274 us; speedup 1.0000x reference)
//
#include <hip/hip_runtime.h>

#define Bn 2048
#define Hn 1024
#define Ln 96
#define Vn 96

typedef short bf16x8 __attribute__((ext_vector_type(8)));
typedef float f32x4 __attribute__((ext_vector_type(4)));

// counted waits: immediates must be literals
#define VM_WAIT(n) asm volatile("s_waitcnt vmcnt(" #n ")" ::: "memory")
// raw barrier with compiler memory fence (no vmcnt drain, unlike __syncthreads)
#define BARRIER    asm volatile("s_barrier" ::: "memory")

__device__ __forceinline__ void async16(const void* g, void* l)
{
    __builtin_amdgcn_global_load_lds(
        (const __attribute__((address_space(1))) void*)g,
        (__attribute__((address_space(3))) void*)l, 16, 0, 0);
}

__device__ __forceinline__ unsigned short f2bf(float f)
{
    unsigned u = __float_as_uint(f);
    u += 0x7fff + ((u >> 16) & 1);          // round-to-nearest-even
    return (unsigned short)(u >> 16);
}

__device__ __forceinline__ float bf2f(unsigned short s)
{
    return __uint_as_float(((unsigned)s) << 16);
}

__device__ __forceinline__ float fast_tanh(float x)
{
    float e = __expf(2.0f * x);
    return 1.0f - __fdividef(2.0f, e + 1.0f);
}

// ---------------------------------------------------------------------------
// Fused step kernel, launch index s (0..97). Grid = 256 blocks x 512 thr
// (8 waves). 128x128 tiles (round-5 verified traffic win) + two new levers:
//
// (1) PAIR SPLIT-K: 4 output quadrants of 64x64, each owned by wave pair
//     (w, w+4); wave w reads k-half 0 of each chunk, w+4 reads k-half 1.
//     Per-wave LDS reads drop 12->8 KB/chunk (block: 96->64 KB/chunk).
//     Epilogue: waves 0-3 dump partial acc to padded f32 LDS (stride 66),
//     waves 4-7 add own acc + bias + tanh and store the 64x64 quadrant.
//
// (2) DEPTH-2 COUNTED STAGING: 3 LDS buffers (96 KB), stage chunk kc+2 at
//     top of chunk kc, VM_WAIT(4) waits only chunk-kc's own 4 loads (each
//     load has ~2 chunk-times in flight). One barrier per chunk.
//
//   bid [0,128)   : L1(t=s-1) 128x128, K=2048 concat (h0@W1i | h1@W1h)
//   bid [128,256) : L0(t=s)   128x128, K=1024; blocks idx<16 then run
//                   FC(t=s-2) 128x96, K=1024 (8-wave quadrants, no split-K)
// All roles read only prior-launch buffers -> no intra-launch ordering.
// LDS slots XOR-swizzled on BOTH the global source column and the ds_read
// address (verified rounds 1-5) -> max 2-way bank aliasing.
// LDS: A 3 bufs x 16 KB + B 3 bufs x 16 KB = 96 KB -> 1 block/CU.
// ---------------------------------------------------------------------------
__global__ __launch_bounds__(512, 1) void fused_step(
    int s,
    const unsigned short* __restrict__ H0rd, unsigned short* __restrict__ H0wr,
    const unsigned short* __restrict__ H1rd, unsigned short* __restrict__ H1wr,
    const unsigned short* __restrict__ W0b,
    const unsigned short* __restrict__ W1ib, const unsigned short* __restrict__ W1hb,
    const unsigned short* __restrict__ fcWb,
    const float* __restrict__ w0ih,
    const float* __restrict__ b0i, const float* __restrict__ b0h,
    const float* __restrict__ b1i, const float* __restrict__ b1h,
    const float* __restrict__ fcb, const float* __restrict__ x,
    float* __restrict__ out)
{
    __shared__ __align__(16) unsigned short smem[49152];   // 96 KB
    const int tid = threadIdx.x;
    const int lane = tid & 63;
    const int wave = tid >> 6;                  // 0..7
    const int srow = lane >> 2;                 // staging row within 16-row chunk
    // stage-side swizzle: lane stores slot (lane&3), fetches global slot
    // (lane&3) ^ g(srow), g(row) = (row>>1)&3  [bijective per row]
    const int scol = ((lane & 3) ^ ((lane >> 3) & 3)) * 8;  // bf16 elems
    const int lr = lane & 15;
    const int lq = lane >> 4;
    // read-side swizzle: global slot lq of row lr lives at stored slot lq^g(lr)
    const int roff = lr * 32 + ((lq ^ ((lr >> 1) & 3)) * 8);
    const int bid = blockIdx.x;

    const bool isL1 = (bid < 128);
    const int idx = bid & 127;
    const bool doMain = isL1 ? (s >= 1 && s <= 96) : (s <= 95);

    // split-K pair geometry
    const int half = wave >> 2;                 // k-half within chunk
    const int qm = (wave >> 1) & 1;             // quadrant row
    const int qn = wave & 1;                    // quadrant col
    const int qoff = ((qm << 1) | qn) * (64 * 66);   // f32 exchange area

    if (doMain) {
        const int bBase = (idx >> 3) * 128;
        const int iBase = (idx & 7) * 128;
        const int NIT = isL1 ? 32 : 16;

        f32x4 acc[4][4];
#pragma unroll
        for (int i = 0; i < 4; ++i)
#pragma unroll
            for (int j = 0; j < 4; ++j) acc[i][j] = (f32x4){0.f, 0.f, 0.f, 0.f};

        auto stage = [&](int ks, int buf) {
            const unsigned short* Ag;
            const unsigned short* Bg;
            int koff;
            if (isL1) {
                Ag = (ks < 16) ? H0rd : H1rd;
                Bg = (ks < 16) ? W1ib : W1hb;
                koff = (ks & 15) * 64;
            } else {
                Ag = H0rd; Bg = W0b; koff = ks * 64;
            }
            if (wave < 4) {
#pragma unroll
                for (int j = 0; j < 4; ++j) {
                    const int id = wave * 4 + j;
                    const int c = id & 7, k2 = id >> 3;
                    async16(Ag + (size_t)(bBase + c * 16 + srow) * Hn + koff + k2 * 32 + scol,
                            smem + buf * 8192 + k2 * 4096 + c * 512);
                }
            } else {
#pragma unroll
                for (int j = 0; j < 4; ++j) {
                    const int id = (wave - 4) * 4 + j;
                    const int c = id & 7, k2 = id >> 3;
                    async16(Bg + (size_t)(iBase + c * 16 + srow) * Hn + koff + k2 * 32 + scol,
                            smem + 24576 + buf * 8192 + k2 * 4096 + c * 512);
                }
            }
        };

        stage(0, 0); stage(1, 1);
        for (int kc = 0; kc < NIT; ++kc) {
            if (kc + 1 < NIT) VM_WAIT(4);       // own chunk-kc loads landed
            else              VM_WAIT(0);
            BARRIER;                            // everyone's chunk-kc landed
            const int cb = kc % 3;
            if (kc + 2 < NIT) stage(kc + 2, (kc + 2) % 3);
            bf16x8 a[4], b[4];
#pragma unroll
            for (int i = 0; i < 4; ++i)
                a[i] = *(const bf16x8*)(smem + cb * 8192 + half * 4096 + (qm * 4 + i) * 512 + roff);
#pragma unroll
            for (int i = 0; i < 4; ++i)
                b[i] = *(const bf16x8*)(smem + 24576 + cb * 8192 + half * 4096 + (qn * 4 + i) * 512 + roff);
            __builtin_amdgcn_s_setprio(1);
#pragma unroll
            for (int mt = 0; mt < 4; ++mt)
#pragma unroll
                for (int nt = 0; nt < 4; ++nt)
                    acc[mt][nt] = __builtin_amdgcn_mfma_f32_16x16x32_bf16(
                        a[mt], b[nt], acc[mt][nt], 0, 0, 0);
            __builtin_amdgcn_s_setprio(0);
        }

        // ---- split-K combine: pair (w, w+4) sums k-halves ----------------
        __syncthreads();                        // all reads of staging LDS done
        float* red = (float*)smem;
        if (wave < 4) {
#pragma unroll
            for (int mt = 0; mt < 4; ++mt)
#pragma unroll
                for (int nt = 0; nt < 4; ++nt)
#pragma unroll
                    for (int r = 0; r < 4; ++r)
                        red[qoff + (mt * 16 + lq * 4 + r) * 66 + nt * 16 + lr] = acc[mt][nt][r];
        }
        __syncthreads();
        if (wave >= 4) {
            if (isL1) {
#pragma unroll
                for (int nt = 0; nt < 4; ++nt) {
                    const int n = iBase + qn * 64 + nt * 16 + lr;
                    const float bs = b1i[n] + b1h[n];
#pragma unroll
                    for (int mt = 0; mt < 4; ++mt)
#pragma unroll
                        for (int r = 0; r < 4; ++r) {
                            const int rl = mt * 16 + lq * 4 + r;
                            float v = acc[mt][nt][r] + red[qoff + rl * 66 + nt * 16 + lr] + bs;
                            H1wr[(size_t)(bBase + qm * 64 + rl) * Hn + n] = f2bf(fast_tanh(v));
                        }
                }
            } else {
#pragma unroll
                for (int nt = 0; nt < 4; ++nt) {
                    const int n = iBase + qn * 64 + nt * 16 + lr;
                    const float wv = w0ih[n];
                    const float bs = b0i[n] + b0h[n];
#pragma unroll
                    for (int mt = 0; mt < 4; ++mt)
#pragma unroll
                        for (int r = 0; r < 4; ++r) {
                            const int rl = mt * 16 + lq * 4 + r;
                            const int bb = bBase + qm * 64 + rl;
                            const float xv = x[bb * Ln + s];
                            float v = acc[mt][nt][r] + red[qoff + rl * 66 + nt * 16 + lr] + xv * wv + bs;
                            H0wr[(size_t)bb * Hn + n] = f2bf(fast_tanh(v));
                        }
                }
            }
        }
    }

    // ================= FC(t = s-2): 128x96, K = 1024 (idx<16) =============
    if (!isL1 && idx < 16 && s >= 2) {
        if (doMain) __syncthreads();            // LDS reuse after L0 epilogue
        const int t = s - 2;
        const int bBase2 = idx * 128;

        f32x4 acc2[2][3];
#pragma unroll
        for (int i = 0; i < 2; ++i)
#pragma unroll
            for (int j = 0; j < 3; ++j) acc2[i][j] = (f32x4){0.f, 0.f, 0.f, 0.f};
        const int mC2 = (wave >> 1) * 2;        // A chunk base
        const int nC2 = (wave & 1) * 3;         // B chunk base

        auto stageF = [&](int ks, int buf) {
            const int koff = ks * 64;
            if (wave < 4) {
#pragma unroll
                for (int j = 0; j < 4; ++j) {
                    const int id = wave * 4 + j;
                    const int c = id & 7, k2 = id >> 3;
                    async16(H1rd + (size_t)(bBase2 + c * 16 + srow) * Hn + koff + k2 * 32 + scol,
                            smem + buf * 8192 + k2 * 4096 + c * 512);
                }
            } else if (wave < 7) {
#pragma unroll
                for (int j = 0; j < 4; ++j) {
                    const int id = (wave - 4) * 4 + j;      // 0..11
                    const int k2 = id / 6, c = id % 6;
                    async16(fcWb + (size_t)(c * 16 + srow) * Hn + koff + k2 * 32 + scol,
                            smem + 24576 + buf * 8192 + k2 * 4096 + c * 512);
                }
            }
        };

        stageF(0, 0); stageF(1, 1);
        for (int kc = 0; kc < 16; ++kc) {
            if (kc + 1 < 16) VM_WAIT(4);
            else             VM_WAIT(0);
            BARRIER;
            const int cb = kc % 3;
            if (kc + 2 < 16) stageF(kc + 2, (kc + 2) % 3);
#pragma unroll
            for (int k2 = 0; k2 < 2; ++k2) {
                bf16x8 a[2], b[3];
#pragma unroll
                for (int mt = 0; mt < 2; ++mt)
                    a[mt] = *(const bf16x8*)(smem + cb * 8192 + k2 * 4096 + (mC2 + mt) * 512 + roff);
#pragma unroll
                for (int nt = 0; nt < 3; ++nt)
                    b[nt] = *(const bf16x8*)(smem + 24576 + cb * 8192 + k2 * 4096 + (nC2 + nt) * 512 + roff);
                __builtin_amdgcn_s_setprio(1);
#pragma unroll
                for (int mt = 0; mt < 2; ++mt)
#pragma unroll
                    for (int nt = 0; nt < 3; ++nt)
                        acc2[mt][nt] = __builtin_amdgcn_mfma_f32_16x16x32_bf16(
                            a[mt], b[nt], acc2[mt][nt], 0, 0, 0);
                __builtin_amdgcn_s_setprio(0);
            }
        }
        {
            const int mB2 = (wave >> 1) * 32;
            const int nB2 = (wave & 1) * 48;
#pragma unroll
            for (int mt = 0; mt < 2; ++mt)
#pragma unroll
                for (int r = 0; r < 4; ++r) {
                    const int row = mB2 + mt * 16 + lq * 4 + r;
                    const size_t o = (size_t)(bBase2 + row) * (Ln * Vn) + (size_t)t * Vn;
#pragma unroll
                    for (int nt = 0; nt < 3; ++nt) {
                        const int n = nB2 + nt * 16 + lr;
                        out[o + n] = acc2[mt][nt][r] + fcb[n];
                    }
                }
        }
    }
}

// ---------------------------------------------------------------------------
// Prologue: convert all 4 weight matrices to bf16 + zero-init H0[0]/H1[0],
// one launch (replaces 4 convert kernels + 2 memsets).
// ---------------------------------------------------------------------------
__global__ void prep_kernel(const float* __restrict__ W0, const float* __restrict__ W1i,
                            const float* __restrict__ W1h, const float* __restrict__ fcW,
                            unsigned short* __restrict__ W0b, unsigned short* __restrict__ W1ib,
                            unsigned short* __restrict__ W1hb, unsigned short* __restrict__ fcWb,
                            unsigned short* __restrict__ H0z, unsigned short* __restrict__ H1z)
{
    const int HH = Hn * Hn;
    const int VH = Vn * Hn;
    const int BH = Bn * Hn;
    const int nconv = 3 * HH + VH;
    const int total = nconv + 2 * BH;
    int i = blockIdx.x * blockDim.x + threadIdx.x;
    const int stride = gridDim.x * blockDim.x;
    for (; i < total; i += stride) {
        if (i < HH)            W0b[i] = f2bf(W0[i]);
        else if (i < 2 * HH)   W1ib[i - HH] = f2bf(W1i[i - HH]);
        else if (i < 3 * HH)   W1hb[i - 2 * HH] = f2bf(W1h[i - 2 * HH]);
        else if (i < nconv)    fcWb[i - 3 * HH] = f2bf(fcW[i - 3 * HH]);
        else if (i < nconv + BH) H0z[i - nconv] = 0;
        else                   H1z[i - nconv - BH] = 0;
    }
}

__global__ void hidden_out(const unsigned short* __restrict__ h0,
                           const unsigned short* __restrict__ h1,
                           float* __restrict__ out)
{
    int i = blockIdx.x * 256 + threadIdx.x;
    out[i] = bf2f(h0[i]);
    out[(size_t)Bn * Hn + i] = bf2f(h1[i]);
}

// ---------------------------------------------------------------------------
// Sequential probability adjustment: one block per batch row b.
// Phase 1 (parallel over t): thread t computes max/argmax over cols != 1
// (m_ex, i_ex) plus v0, v1 — float4 loads, first-index tie rule.
// Phase 2 (thread 0): 96-step scalar recurrence on the precomputed stats;
// only col 1 is ever modified mid-scan, so the adjusted argmax follows from
// (v1 [+0.5], m_ex, i_ex) alone. Writes only the modified cells.
// ---------------------------------------------------------------------------
__global__ __launch_bounds__(128) void adjust_kernel(float* __restrict__ out)
{
    __shared__ float s_mex[Ln], s_v0[Ln], s_v1[Ln];
    __shared__ int   s_iex[Ln];
    const int b = blockIdx.x;
    const int t = threadIdx.x;
    float* row = out + (size_t)b * (Ln * Vn);

    if (t < Ln) {
        const float4* r4 = (const float4*)(row + t * Vn);
        float4 q = r4[0];
        float m = q.x; int im = 0;                 // col 0 included, col 1 excluded
        if (q.z > m) { m = q.z; im = 2; }
        if (q.w > m) { m = q.w; im = 3; }
        const float v0 = q.x, v1 = q.y;
        for (int jj = 1; jj < 24; ++jj) {
            float4 p = r4[jj];
            const int base = jj * 4;
            if (p.x > m) { m = p.x; im = base; }
            if (p.y > m) { m = p.y; im = base + 1; }
            if (p.z > m) { m = p.z; im = base + 2; }
            if (p.w > m) { m = p.w; im = base + 3; }
        }
        s_mex[t] = m; s_iex[t] = im; s_v0[t] = v0; s_v1[t] = v1;
    }
    __syncthreads();

    if (t == 0) {
        // argmax(row) with first-index ties: 1 wins over im iff v1>m, or
        // v1==m and im!=0 (im is in {0,2,3,...}).
        float v1p = s_v1[0]; float mp = s_mex[0]; int ip = s_iex[0];
        int prev = (v1p > mp || (v1p == mp && ip != 0)) ? 1 : ip;
        for (int k = 1; k < Ln; ++k) {
            const float v1c = s_v1[k];
            const float mc = s_mex[k];
            const int ic = s_iex[k];
            const int cur = (v1c > mc || (v1c == mc && ic != 0)) ? 1 : ic;
            float v1a = v1c;
            if (prev == 0 && cur != 1) {
                v1a = v1c + 0.5f;
                row[k * Vn + 1] = v1a;
            }
            if (k == Ln - 1 && cur == 0)
                row[k * Vn + 0] = s_v0[k] - 0.5f;
            prev = (v1a > mc || (v1a == mc && ic != 0)) ? 1 : ic;
        }
    }
}

// ---------------------------------------------------------------------------
extern "C" void kernel_launch(void* const* d_in, const int* in_sizes, int n_in,
                              void* d_out, int out_size, void* d_ws, size_t ws_size,
                              hipStream_t stream)
{
    const float* x    = (const float*)d_in[0];
    const float* w0ih = (const float*)d_in[1];
    const float* W0   = (const float*)d_in[2];
    const float* b0i  = (const float*)d_in[3];
    const float* b0h  = (const float*)d_in[4];
    const float* W1i  = (const float*)d_in[5];
    const float* W1h  = (const float*)d_in[6];
    const float* b1i  = (const float*)d_in[7];
    const float* b1h  = (const float*)d_in[8];
    const float* fcW  = (const float*)d_in[9];
    const float* fcb  = (const float*)d_in[10];
    float* out = (float*)d_out;

    const size_t HH = (size_t)Hn * Hn;
    const size_t BH = (size_t)Bn * Hn;
    unsigned short* ws = (unsigned short*)d_ws;
    unsigned short* W0b  = ws;
    unsigned short* W1ib = ws + HH;
    unsigned short* W1hb = ws + 2 * HH;
    unsigned short* fcWb = ws + 3 * HH;
    unsigned short* H0[2] = { ws + 4 * HH,          ws + 4 * HH + BH };
    unsigned short* H1[2] = { ws + 4 * HH + 2 * BH, ws + 4 * HH + 3 * BH };

    // convert weights + zero h0(-1)/h1(-1) in one launch
    prep_kernel<<<dim3(1024), dim3(256), 0, stream>>>(
        W0, W1i, W1h, fcW, W0b, W1ib, W1hb, fcWb, H0[0], H1[0]);

    // Launch s computes: L0(s) [s<=95], L1(s-1) [s>=1], FC(s-2) [s>=2].
    // h0(t) lives in H0[(t+1)&1]; h1(t) in H1[(t+1)&1].
    for (int s = 0; s <= 97; ++s) {
        fused_step<<<dim3(256), dim3(512), 0, stream>>>(
            s,
            H0[s & 1], H0[(s + 1) & 1],          // L0 read / write
            H1[(s + 1) & 1], H1[s & 1],          // h1(s-2) read / h1(s-1) write
            W0b, W1ib, W1hb, fcWb,
            w0ih, b0i, b0h, b1i, b1h, fcb, x, out);
    }

    adjust_kernel<<<dim3(Bn), dim3(128), 0, stream>>>(out);

    // final states: h0(95) = H0[0], h1(95) = H1[0]
    hidden_out<<<dim3((int)(BH / 256)), dim3(256), 0, stream>>>(
        H0[0], H1[0], out + (size_t)Bn * Ln * Vn);
}

// Round 7
// 2432.785 us; speedup vs baseline: 1.4396x; 1.4396x over previous
//
#include <hip/hip_runtime.h>

#define Bn 2048
#define Hn 1024
#define Ln 96
#define Vn 96

typedef short bf16x8 __attribute__((ext_vector_type(8)));
typedef float f32x4 __attribute__((ext_vector_type(4)));

// counted waits: immediates must be literals
#define VM_WAIT(n) asm volatile("s_waitcnt vmcnt(" #n ")" ::: "memory")
// raw barrier with compiler memory fence (no vmcnt drain, unlike __syncthreads)
#define BARRIER    asm volatile("s_barrier" ::: "memory")

__device__ __forceinline__ void async16(const void* g, void* l)
{
    __builtin_amdgcn_global_load_lds(
        (const __attribute__((address_space(1))) void*)g,
        (__attribute__((address_space(3))) void*)l, 16, 0, 0);
}

__device__ __forceinline__ unsigned short f2bf(float f)
{
    unsigned u = __float_as_uint(f);
    u += 0x7fff + ((u >> 16) & 1);          // round-to-nearest-even
    return (unsigned short)(u >> 16);
}

__device__ __forceinline__ float bf2f(unsigned short s)
{
    return __uint_as_float(((unsigned)s) << 16);
}

__device__ __forceinline__ float fast_tanh(float x)
{
    float e = __expf(2.0f * x);
    return 1.0f - __fdividef(2.0f, e + 1.0f);
}

// ---------------------------------------------------------------------------
// Fused step kernel, launch index s (0..97). Grid = 256 blocks x 512 thr
// (8 waves). EXACT round-5 schedule (verified 2879 us) with ONE change:
// K-chunk 64 -> 128. Chunks halve (L1 32->16, L0 16->8, FC 16->8), per-chunk
// compute doubles (32 MFMAs + 24 ds_reads per wave), so the same-chunk
// prefetch drain is covered ~2x better and barrier count halves.
//
//   bid [0,128)   : L1(t=s-1) 128x128, K=2048 concat: chunks 0-7 from
//                   (h0(s-1), W1i), 8-15 from (h1(s-2), W1h). acc carries the
//                   dual-GEMM sum -> no cross-wave reduce.
//   bid [128,256) : L0(t=s)   128x128, K=1024 (8 chunks); blocks idx<16 then
//                   run FC(t=s-2) 128x96, K=1024 (8 chunks).
// Schedule per chunk (round-5 verified): stage(kc+1) at top -> compute kc
// (4 k2-clusters of [6 ds_read_b128 + 8 MFMA, setprio-wrapped]) ->
// VM_WAIT(0) -> BARRIER. Cooperative staging: waves 0-3 stage A (8 loads
// each, wave = k2 subchunk), waves 4-7 stage B. Per-wave output 64x32.
// LDS slots XOR-swizzled on BOTH the global source column and the ds_read
// address (verified rounds 1-5) -> max 2-way bank aliasing.
// LDS: A 2 bufs x 32 KB + B 2 bufs x 32 KB = 128 KB -> 1 block/CU.
// ---------------------------------------------------------------------------
__global__ __launch_bounds__(512, 1) void fused_step(
    int s,
    const unsigned short* __restrict__ H0rd, unsigned short* __restrict__ H0wr,
    const unsigned short* __restrict__ H1rd, unsigned short* __restrict__ H1wr,
    const unsigned short* __restrict__ W0b,
    const unsigned short* __restrict__ W1ib, const unsigned short* __restrict__ W1hb,
    const unsigned short* __restrict__ fcWb,
    const float* __restrict__ w0ih,
    const float* __restrict__ b0i, const float* __restrict__ b0h,
    const float* __restrict__ b1i, const float* __restrict__ b1h,
    const float* __restrict__ fcb, const float* __restrict__ x,
    float* __restrict__ out)
{
    __shared__ __align__(16) unsigned short smem[65536];   // 128 KB
    const int tid = threadIdx.x;
    const int lane = tid & 63;
    const int wave = tid >> 6;                  // 0..7
    const int srow = lane >> 2;                 // staging row within 16-row chunk
    // stage-side swizzle: lane stores slot (lane&3), fetches global slot
    // (lane&3) ^ g(srow), g(row) = (row>>1)&3  [bijective per row]
    const int scol = ((lane & 3) ^ ((lane >> 3) & 3)) * 8;  // bf16 elems
    const int lr = lane & 15;
    const int lq = lane >> 4;
    // read-side swizzle: global slot lq of row lr lives at stored slot lq^g(lr)
    const int roff = lr * 32 + ((lq ^ ((lr >> 1) & 3)) * 8);
    const int bid = blockIdx.x;

    // LDS layout (elements): A: buf*16384 + k2*4096 + c*512   (k2<4, c<8)
    //                        B: 32768 + same   (FC: B buf*12288 + k2*3072 + c*512, c<6)
    if (bid < 128) {
        // ================= L1(t = s-1): 128x128, K = 2048 concat ==========
        if (s < 1 || s > 96) return;
        const int bBase = (bid >> 3) * 128;
        const int iBase = (bid & 7) * 128;

        f32x4 acc[4][2];
#pragma unroll
        for (int i = 0; i < 4; ++i) {
            acc[i][0] = (f32x4){0.f, 0.f, 0.f, 0.f};
            acc[i][1] = (f32x4){0.f, 0.f, 0.f, 0.f};
        }
        const int mC = (wave >> 2) * 4;         // A 16-row-chunk base for frags
        const int nC = (wave & 3) * 2;          // B chunk base

        auto stage = [&](int ks, int buf) {
            const unsigned short* Ag = (ks < 8) ? H0rd : H1rd;
            const unsigned short* Bg = (ks < 8) ? W1ib : W1hb;
            const int koff = (ks & 7) * 128;
            if (wave < 4) {
#pragma unroll
                for (int j = 0; j < 8; ++j)
                    async16(Ag + (size_t)(bBase + j * 16 + srow) * Hn + koff + wave * 32 + scol,
                            smem + buf * 16384 + wave * 4096 + j * 512);
            } else {
#pragma unroll
                for (int j = 0; j < 8; ++j)
                    async16(Bg + (size_t)(iBase + j * 16 + srow) * Hn + koff + (wave - 4) * 32 + scol,
                            smem + 32768 + buf * 16384 + (wave - 4) * 4096 + j * 512);
            }
        };

        stage(0, 0); VM_WAIT(0); BARRIER;
        for (int kc = 0; kc < 16; ++kc) {
            if (kc + 1 < 16) stage(kc + 1, (kc + 1) & 1);
            const int buf = kc & 1;
#pragma unroll
            for (int k2 = 0; k2 < 4; ++k2) {
                bf16x8 a[4], b[2];
#pragma unroll
                for (int mt = 0; mt < 4; ++mt)
                    a[mt] = *(const bf16x8*)(smem + buf * 16384 + k2 * 4096 + (mC + mt) * 512 + roff);
#pragma unroll
                for (int nt = 0; nt < 2; ++nt)
                    b[nt] = *(const bf16x8*)(smem + 32768 + buf * 16384 + k2 * 4096 + (nC + nt) * 512 + roff);
                __builtin_amdgcn_s_setprio(1);
#pragma unroll
                for (int mt = 0; mt < 4; ++mt)
#pragma unroll
                    for (int nt = 0; nt < 2; ++nt)
                        acc[mt][nt] = __builtin_amdgcn_mfma_f32_16x16x32_bf16(
                            a[mt], b[nt], acc[mt][nt], 0, 0, 0);
                __builtin_amdgcn_s_setprio(0);
            }
            VM_WAIT(0); BARRIER;
        }
        // epilogue: wave owns rows [ (wave>>2)*64, +64 ), cols [ (wave&3)*32, +32 )
        {
            const int mB = (wave >> 2) * 64;
            const int nB = (wave & 3) * 32;
#pragma unroll
            for (int nt = 0; nt < 2; ++nt) {
                const int n = iBase + nB + nt * 16 + lr;
                const float bs = b1i[n] + b1h[n];
#pragma unroll
                for (int mt = 0; mt < 4; ++mt)
#pragma unroll
                    for (int r = 0; r < 4; ++r) {
                        const int row = mB + mt * 16 + lq * 4 + r;
                        float v = acc[mt][nt][r] + bs;
                        H1wr[(size_t)(bBase + row) * Hn + n] = f2bf(fast_tanh(v));
                    }
            }
        }
    } else {
        // ============ L0(t = s): 128x128, K = 1024; idx<16 then FC ========
        const int idx = bid - 128;
        if (s <= 95) {
            const int bBase = (idx >> 3) * 128;
            const int iBase = (idx & 7) * 128;

            f32x4 acc[4][2];
#pragma unroll
            for (int i = 0; i < 4; ++i) {
                acc[i][0] = (f32x4){0.f, 0.f, 0.f, 0.f};
                acc[i][1] = (f32x4){0.f, 0.f, 0.f, 0.f};
            }
            const int mC = (wave >> 2) * 4;
            const int nC = (wave & 3) * 2;

            auto stage = [&](int ks, int buf) {
                const int koff = ks * 128;
                if (wave < 4) {
#pragma unroll
                    for (int j = 0; j < 8; ++j)
                        async16(H0rd + (size_t)(bBase + j * 16 + srow) * Hn + koff + wave * 32 + scol,
                                smem + buf * 16384 + wave * 4096 + j * 512);
                } else {
#pragma unroll
                    for (int j = 0; j < 8; ++j)
                        async16(W0b + (size_t)(iBase + j * 16 + srow) * Hn + koff + (wave - 4) * 32 + scol,
                                smem + 32768 + buf * 16384 + (wave - 4) * 4096 + j * 512);
                }
            };

            stage(0, 0); VM_WAIT(0); BARRIER;
            for (int kc = 0; kc < 8; ++kc) {
                if (kc + 1 < 8) stage(kc + 1, (kc + 1) & 1);
                const int buf = kc & 1;
#pragma unroll
                for (int k2 = 0; k2 < 4; ++k2) {
                    bf16x8 a[4], b[2];
#pragma unroll
                    for (int mt = 0; mt < 4; ++mt)
                        a[mt] = *(const bf16x8*)(smem + buf * 16384 + k2 * 4096 + (mC + mt) * 512 + roff);
#pragma unroll
                    for (int nt = 0; nt < 2; ++nt)
                        b[nt] = *(const bf16x8*)(smem + 32768 + buf * 16384 + k2 * 4096 + (nC + nt) * 512 + roff);
                    __builtin_amdgcn_s_setprio(1);
#pragma unroll
                    for (int mt = 0; mt < 4; ++mt)
#pragma unroll
                        for (int nt = 0; nt < 2; ++nt)
                            acc[mt][nt] = __builtin_amdgcn_mfma_f32_16x16x32_bf16(
                                a[mt], b[nt], acc[mt][nt], 0, 0, 0);
                    __builtin_amdgcn_s_setprio(0);
                }
                VM_WAIT(0); BARRIER;
            }
            {
                const int mB = (wave >> 2) * 64;
                const int nB = (wave & 3) * 32;
#pragma unroll
                for (int nt = 0; nt < 2; ++nt) {
                    const int n = iBase + nB + nt * 16 + lr;
                    const float wv = w0ih[n];
                    const float bs = b0i[n] + b0h[n];
#pragma unroll
                    for (int mt = 0; mt < 4; ++mt)
#pragma unroll
                        for (int r = 0; r < 4; ++r) {
                            const int row = mB + mt * 16 + lq * 4 + r;
                            const int bb = bBase + row;
                            const float xv = x[bb * Ln + s];
                            float v = acc[mt][nt][r] + xv * wv + bs;
                            H0wr[(size_t)bb * Hn + n] = f2bf(fast_tanh(v));
                        }
                }
            }
        }
        // ================= FC(t = s-2): 128x96, K = 1024 ==================
        if (idx < 16 && s >= 2) {
            __syncthreads();                    // LDS reuse after L0 (if it ran)
            const int t = s - 2;
            const int bBase2 = idx * 128;

            f32x4 acc2[2][3];
#pragma unroll
            for (int i = 0; i < 2; ++i)
#pragma unroll
                for (int j = 0; j < 3; ++j) acc2[i][j] = (f32x4){0.f, 0.f, 0.f, 0.f};
            const int mC2 = (wave >> 1) * 2;    // A chunk base
            const int nC2 = (wave & 1) * 3;     // B chunk base

            auto stageF = [&](int ks, int buf) {
                const int koff = ks * 128;
                if (wave < 4) {
#pragma unroll
                    for (int j = 0; j < 8; ++j)
                        async16(H1rd + (size_t)(bBase2 + j * 16 + srow) * Hn + koff + wave * 32 + scol,
                                smem + buf * 16384 + wave * 4096 + j * 512);
                } else {
#pragma unroll
                    for (int j = 0; j < 6; ++j) {
                        const int id = (wave - 4) * 6 + j;      // 0..23
                        const int k2 = id / 6, c = id % 6;
                        async16(fcWb + (size_t)(c * 16 + srow) * Hn + koff + k2 * 32 + scol,
                                smem + 32768 + buf * 12288 + k2 * 3072 + c * 512);
                    }
                }
            };

            stageF(0, 0); VM_WAIT(0); BARRIER;
            for (int kc = 0; kc < 8; ++kc) {
                if (kc + 1 < 8) stageF(kc + 1, (kc + 1) & 1);
                const int buf = kc & 1;
#pragma unroll
                for (int k2 = 0; k2 < 4; ++k2) {
                    bf16x8 a[2], b[3];
#pragma unroll
                    for (int mt = 0; mt < 2; ++mt)
                        a[mt] = *(const bf16x8*)(smem + buf * 16384 + k2 * 4096 + (mC2 + mt) * 512 + roff);
#pragma unroll
                    for (int nt = 0; nt < 3; ++nt)
                        b[nt] = *(const bf16x8*)(smem + 32768 + buf * 12288 + k2 * 3072 + (nC2 + nt) * 512 + roff);
                    __builtin_amdgcn_s_setprio(1);
#pragma unroll
                    for (int mt = 0; mt < 2; ++mt)
#pragma unroll
                        for (int nt = 0; nt < 3; ++nt)
                            acc2[mt][nt] = __builtin_amdgcn_mfma_f32_16x16x32_bf16(
                                a[mt], b[nt], acc2[mt][nt], 0, 0, 0);
                    __builtin_amdgcn_s_setprio(0);
                }
                VM_WAIT(0); BARRIER;
            }
            {
                const int mB2 = (wave >> 1) * 32;
                const int nB2 = (wave & 1) * 48;
#pragma unroll
                for (int mt = 0; mt < 2; ++mt)
#pragma unroll
                    for (int r = 0; r < 4; ++r) {
                        const int row = mB2 + mt * 16 + lq * 4 + r;
                        const size_t o = (size_t)(bBase2 + row) * (Ln * Vn) + (size_t)t * Vn;
#pragma unroll
                        for (int nt = 0; nt < 3; ++nt) {
                            const int n = nB2 + nt * 16 + lr;
                            out[o + n] = acc2[mt][nt][r] + fcb[n];
                        }
                    }
            }
        }
    }
}

// ---------------------------------------------------------------------------
// Prologue: convert all 4 weight matrices to bf16 + zero-init H0[0]/H1[0],
// one launch (replaces 4 convert kernels + 2 memsets).
// ---------------------------------------------------------------------------
__global__ void prep_kernel(const float* __restrict__ W0, const float* __restrict__ W1i,
                            const float* __restrict__ W1h, const float* __restrict__ fcW,
                            unsigned short* __restrict__ W0b, unsigned short* __restrict__ W1ib,
                            unsigned short* __restrict__ W1hb, unsigned short* __restrict__ fcWb,
                            unsigned short* __restrict__ H0z, unsigned short* __restrict__ H1z)
{
    const int HH = Hn * Hn;
    const int VH = Vn * Hn;
    const int BH = Bn * Hn;
    const int nconv = 3 * HH + VH;
    const int total = nconv + 2 * BH;
    int i = blockIdx.x * blockDim.x + threadIdx.x;
    const int stride = gridDim.x * blockDim.x;
    for (; i < total; i += stride) {
        if (i < HH)            W0b[i] = f2bf(W0[i]);
        else if (i < 2 * HH)   W1ib[i - HH] = f2bf(W1i[i - HH]);
        else if (i < 3 * HH)   W1hb[i - 2 * HH] = f2bf(W1h[i - 2 * HH]);
        else if (i < nconv)    fcWb[i - 3 * HH] = f2bf(fcW[i - 3 * HH]);
        else if (i < nconv + BH) H0z[i - nconv] = 0;
        else                   H1z[i - nconv - BH] = 0;
    }
}

__global__ void hidden_out(const unsigned short* __restrict__ h0,
                           const unsigned short* __restrict__ h1,
                           float* __restrict__ out)
{
    int i = blockIdx.x * 256 + threadIdx.x;
    out[i] = bf2f(h0[i]);
    out[(size_t)Bn * Hn + i] = bf2f(h1[i]);
}

// ---------------------------------------------------------------------------
// Sequential probability adjustment: one block per batch row b.
// Phase 1 (parallel over t): thread t computes max/argmax over cols != 1
// (m_ex, i_ex) plus v0, v1 — float4 loads, first-index tie rule.
// Phase 2 (thread 0): 96-step scalar recurrence on the precomputed stats;
// only col 1 is ever modified mid-scan, so the adjusted argmax follows from
// (v1 [+0.5], m_ex, i_ex) alone. Writes only the modified cells.
// ---------------------------------------------------------------------------
__global__ __launch_bounds__(128) void adjust_kernel(float* __restrict__ out)
{
    __shared__ float s_mex[Ln], s_v0[Ln], s_v1[Ln];
    __shared__ int   s_iex[Ln];
    const int b = blockIdx.x;
    const int t = threadIdx.x;
    float* row = out + (size_t)b * (Ln * Vn);

    if (t < Ln) {
        const float4* r4 = (const float4*)(row + t * Vn);
        float4 q = r4[0];
        float m = q.x; int im = 0;                 // col 0 included, col 1 excluded
        if (q.z > m) { m = q.z; im = 2; }
        if (q.w > m) { m = q.w; im = 3; }
        const float v0 = q.x, v1 = q.y;
        for (int jj = 1; jj < 24; ++jj) {
            float4 p = r4[jj];
            const int base = jj * 4;
            if (p.x > m) { m = p.x; im = base; }
            if (p.y > m) { m = p.y; im = base + 1; }
            if (p.z > m) { m = p.z; im = base + 2; }
            if (p.w > m) { m = p.w; im = base + 3; }
        }
        s_mex[t] = m; s_iex[t] = im; s_v0[t] = v0; s_v1[t] = v1;
    }
    __syncthreads();

    if (t == 0) {
        // argmax(row) with first-index ties: 1 wins over im iff v1>m, or
        // v1==m and im!=0 (im is in {0,2,3,...}).
        float v1p = s_v1[0]; float mp = s_mex[0]; int ip = s_iex[0];
        int prev = (v1p > mp || (v1p == mp && ip != 0)) ? 1 : ip;
        for (int k = 1; k < Ln; ++k) {
            const float v1c = s_v1[k];
            const float mc = s_mex[k];
            const int ic = s_iex[k];
            const int cur = (v1c > mc || (v1c == mc && ic != 0)) ? 1 : ic;
            float v1a = v1c;
            if (prev == 0 && cur != 1) {
                v1a = v1c + 0.5f;
                row[k * Vn + 1] = v1a;
            }
            if (k == Ln - 1 && cur == 0)
                row[k * Vn + 0] = s_v0[k] - 0.5f;
            prev = (v1a > mc || (v1a == mc && ic != 0)) ? 1 : ic;
        }
    }
}

// ---------------------------------------------------------------------------
extern "C" void kernel_launch(void* const* d_in, const int* in_sizes, int n_in,
                              void* d_out, int out_size, void* d_ws, size_t ws_size,
                              hipStream_t stream)
{
    const float* x    = (const float*)d_in[0];
    const float* w0ih = (const float*)d_in[1];
    const float* W0   = (const float*)d_in[2];
    const float* b0i  = (const float*)d_in[3];
    const float* b0h  = (const float*)d_in[4];
    const float* W1i  = (const float*)d_in[5];
    const float* W1h  = (const float*)d_in[6];
    const float* b1i  = (const float*)d_in[7];
    const float* b1h  = (const float*)d_in[8];
    const float* fcW  = (const float*)d_in[9];
    const float* fcb  = (const float*)d_in[10];
    float* out = (float*)d_out;

    const size_t HH = (size_t)Hn * Hn;
    const size_t BH = (size_t)Bn * Hn;
    unsigned short* ws = (unsigned short*)d_ws;
    unsigned short* W0b  = ws;
    unsigned short* W1ib = ws + HH;
    unsigned short* W1hb = ws + 2 * HH;
    unsigned short* fcWb = ws + 3 * HH;
    unsigned short* H0[2] = { ws + 4 * HH,          ws + 4 * HH + BH };
    unsigned short* H1[2] = { ws + 4 * HH + 2 * BH, ws + 4 * HH + 3 * BH };

    // convert weights + zero h0(-1)/h1(-1) in one launch
    prep_kernel<<<dim3(1024), dim3(256), 0, stream>>>(
        W0, W1i, W1h, fcW, W0b, W1ib, W1hb, fcWb, H0[0], H1[0]);

    // Launch s computes: L0(s) [s<=95], L1(s-1) [s>=1], FC(s-2) [s>=2].
    // h0(t) lives in H0[(t+1)&1]; h1(t) in H1[(t+1)&1].
    for (int s = 0; s <= 97; ++s) {
        fused_step<<<dim3(256), dim3(512), 0, stream>>>(
            s,
            H0[s & 1], H0[(s + 1) & 1],          // L0 read / write
            H1[(s + 1) & 1], H1[s & 1],          // h1(s-2) read / h1(s-1) write
            W0b, W1ib, W1hb, fcWb,
            w0ih, b0i, b0h, b1i, b1h, fcb, x, out);
    }

    adjust_kernel<<<dim3(Bn), dim3(128), 0, stream>>>(out);

    // final states: h0(95) = H0[0], h1(95) = H1[0]
    hidden_out<<<dim3((int)(BH / 256)), dim3(256), 0, stream>>>(
        H0[0], H1[0], out + (size_t)Bn * Ln * Vn);
}